// Round 16
// baseline (170.765 us; speedup 1.0000x reference)
//
#include <hip/hip_runtime.h>
#include <math.h>

typedef __attribute__((ext_vector_type(8))) short short8;
typedef __attribute__((ext_vector_type(4))) short short4v;
typedef __attribute__((ext_vector_type(4))) float f32x4;
typedef __attribute__((ext_vector_type(4))) unsigned int u32x4;

// wpack v2 layout (bytes), XOR-swizzled rows (off ^= (row&7)<<4 within row):
//   w1 : 128 rows x 128B  (row n: [64B hi k=0..31][64B lo]; k>=16 zero; W1[k][n])
//   w2 : 128 rows x 512B  (row n: [256B hi k=0..127][256B lo]; W2[k][n])
//   w3 : 4 rows   x 512B  (unused by K2 since round 16; kept for layout stability)
//   b1,b2 : 128 f32 each; b3 : 4 f32; zero pad to 86016
#define OFF_W1 0
#define OFF_W2 16384
#define OFF_W3 81920
#define OFF_B1 83968
#define OFF_B2 84480
#define OFF_B3 84992
#define WPACK_BYTES 86016

__device__ __forceinline__ unsigned short f2bf(float x) {
    union { float f; unsigned u; } v; v.f = x;
    unsigned r = v.u + 0x7FFF + ((v.u >> 16) & 1);   // RNE
    return (unsigned short)(r >> 16);
}
__device__ __forceinline__ float bf2f(unsigned short h) {
    union { unsigned u; float f; } v; v.u = ((unsigned)h) << 16;
    return v.f;
}
__device__ __forceinline__ float asf(unsigned u) {
    union { unsigned u; float f; } v; v.u = u; return v.f;
}
// v_cvt_pk_bf16_f32: dst.lo16 = bf16(a), dst.hi16 = bf16(b), RNE (same as f2bf)
__device__ __forceinline__ unsigned cvtpk(float a, float b) {
    unsigned d;
    asm("v_cvt_pk_bf16_f32 %0, %1, %2" : "=v"(d) : "v"(a), "v"(b));
    return d;
}
// v_perm_b32: data = {s0:bytes4-7, s1:bytes0-3}; dst.byte_i = data.byte[sel_i]
__device__ __forceinline__ unsigned permb(unsigned s0, unsigned s1, unsigned sel) {
    unsigned d;
    asm("v_perm_b32 %0, %1, %2, %3" : "=v"(d) : "v"(s0), "v"(s1), "s"(sel));
    return d;
}

// ---------------------------------------------------------------------------
// K0: pack weights into split-bf16 (hi/lo), swizzle baked into global layout.
// (verbatim — validated)
// ---------------------------------------------------------------------------
__global__ __launch_bounds__(256) void pack_weights_kernel(
    const float* __restrict__ W1, const float* __restrict__ b1,
    const float* __restrict__ W2, const float* __restrict__ b2,
    const float* __restrict__ W3, const float* __restrict__ b3,
    char* __restrict__ wp)
{
    int s = blockIdx.x * 256 + threadIdx.x;       // ushort slot
    if (s >= WPACK_BYTES / 2) return;
    int b = s * 2;
    if (b < OFF_W2) {                             // w1
        int rr = b >> 7;
        int off = (b & 127) ^ ((rr & 7) << 4);
        int k = (off & 63) >> 1;
        float x = (k < 16) ? W1[k * 128 + rr] : 0.0f;
        unsigned short hi = f2bf(x);
        *(unsigned short*)(wp + b) = (off < 64) ? hi : f2bf(x - bf2f(hi));
    } else if (b < OFF_W3) {                      // w2
        int i = b - OFF_W2;
        int rr = i >> 9;
        int off = (i & 511) ^ ((rr & 7) << 4);
        int k = (off & 255) >> 1;
        float x = W2[k * 128 + rr];
        unsigned short hi = f2bf(x);
        *(unsigned short*)(wp + b) = (off < 256) ? hi : f2bf(x - bf2f(hi));
    } else if (b < OFF_B1) {                      // w3 (unused by K2, kept)
        int i = b - OFF_W3;
        int rr = i >> 9;                          // 0..3
        int off = (i & 511) ^ ((rr & 7) << 4);
        int k = (off & 255) >> 1;
        float x = W3[k * 4 + rr];
        unsigned short hi = f2bf(x);
        *(unsigned short*)(wp + b) = (off < 256) ? hi : f2bf(x - bf2f(hi));
    } else if (b < OFF_B3 + 16) {                 // f32 biases
        if ((b & 3) == 0) {
            float v;
            if (b < OFF_B2)      v = b1[(b - OFF_B1) >> 2];
            else if (b < OFF_B3) v = b2[(b - OFF_B2) >> 2];
            else                 v = b3[(b - OFF_B3) >> 2];
            *(float*)(wp + b) = v;
        }
    } else {
        *(unsigned short*)(wp + b) = 0;
    }
}

// ---------------------------------------------------------------------------
// K1: conv encoder, both views per thread, writes relu'd-then-averaged volume
// (validated round 11). vols[sb][dz][y][x][c], fp32, 33.5 MB.
// ---------------------------------------------------------------------------
__global__ __launch_bounds__(256) void conv_enc_avg_kernel(
    const float* __restrict__ images,
    const float* __restrict__ W_enc,
    const float* __restrict__ b_enc,
    float* __restrict__ vols)
{
    __shared__ float wl[16 * 27];
    __shared__ float bl[16];
    int t = threadIdx.x;
    int gid = blockIdx.x * 256 + t;   // 0 .. 2^19-1
    int ow = gid & 63;
    int oh = (gid >> 6) & 63;
    int dz = (gid >> 12) & 63;
    int sb = gid >> 18;               // 0..1

    for (int i = t; i < 16 * 27; i += 256) {
        int c = i / 27, r = i - c * 27;
        wl[i] = W_enc[(c * 64 + dz) * 27 + r];
    }
    if (t < 16) bl[t] = b_enc[t * 64 + dz];
    __syncthreads();

    const float* img0 = images + (size_t)((sb * 3 + 0) * 3) * (128 * 128);
    const float* img1 = images + (size_t)((sb * 3 + 1) * 3) * (128 * 128);

    float acc0[16], acc1[16];
#pragma unroll
    for (int c = 0; c < 16; ++c) { acc0[c] = 0.0f; acc1[c] = 0.0f; }

#pragma unroll
    for (int ci = 0; ci < 3; ++ci) {
#pragma unroll
        for (int kh = 0; kh < 3; ++kh) {
            int ih = oh * 2 + kh;
            if (ih >= 128) continue;
#pragma unroll
            for (int kw = 0; kw < 3; ++kw) {
                int iw = ow * 2 + kw;
                if (iw >= 128) continue;
                float p0 = img0[(ci * 128 + ih) * 128 + iw];
                float p1 = img1[(ci * 128 + ih) * 128 + iw];
                const float* w = &wl[ci * 9 + kh * 3 + kw];
#pragma unroll
                for (int c = 0; c < 16; ++c) {
                    float wv = w[c * 27];
                    acc0[c] = fmaf(p0, wv, acc0[c]);
                    acc1[c] = fmaf(p1, wv, acc1[c]);
                }
            }
        }
    }

    float* outp = vols + ((((size_t)sb * 64 + dz) * 64 + oh) * 64 + ow) * 16;
    float r[16];
#pragma unroll
    for (int c = 0; c < 16; ++c) {
        float v0 = fmaxf(acc0[c] + bl[c], 0.0f);
        float v1 = fmaxf(acc1[c] + bl[c], 0.0f);
        r[c] = (v0 + v1) * 0.5f;
    }
#pragma unroll
    for (int q = 0; q < 4; ++q) {
        float4 v = make_float4(r[q * 4], r[q * 4 + 1], r[q * 4 + 2], r[q * 4 + 3]);
        *(float4*)(outp + q * 4) = v;
    }
}

// ---------------------------------------------------------------------------
// Gather one point's 8 trilinear corners + weights into registers (no combine)
// ---------------------------------------------------------------------------
__device__ __forceinline__ void gather_pt(
    const float* __restrict__ vols, const float* __restrict__ rays,
    int tile, int prow, int cg, float4 cv[8], float wt[8])
{
    int sb = tile >> 12;
    int n0 = (tile & 4095) << 6;
    int n = n0 + prow;
    int i_s = n >> 12, pix = n & 4095;
    const float* ray = rays + ((size_t)sb * 4096 + pix) * 8;
    float ox = ray[0], oy = ray[1], oz = ray[2];
    float rdx = ray[3], rdy = ray[4], rdz = ray[5];
    float nr = ray[6], fr = ray[7];
    float tt = ((float)i_s + 0.5f) * (1.0f / 64.0f);
    float zv = nr * (1.0f - tt) + fr * tt;
    float px = fmaf(rdx, zv, ox);
    float py = fmaf(rdy, zv, oy);
    float pz = fmaf(rdz, zv, oz);
    float cx = fminf(fmaxf(px * (1.0f / 3.5f), -1.0f), 1.0f);
    float cy = fminf(fmaxf(py * (1.0f / 3.5f), -1.0f), 1.0f);
    float cz = fminf(fmaxf(pz * (1.0f / 3.5f), -1.0f), 1.0f);
    float ux = (cx + 1.0f) * 31.5f;
    float uy = (cy + 1.0f) * 31.5f;
    float uz = (cz + 1.0f) * 31.5f;
    int x0 = (int)fminf(floorf(ux), 62.0f);
    int y0 = (int)fminf(floorf(uy), 62.0f);
    int z0 = (int)fminf(floorf(uz), 62.0f);
    float fx = ux - (float)x0;
    float fy = uy - (float)y0;
    float fz = uz - (float)z0;
    float wxa[2] = {1.0f - fx, fx};
    float wya[2] = {1.0f - fy, fy};
    float wza[2] = {1.0f - fz, fz};
    const float* vb = vols + (size_t)sb * (64 * 64 * 64 * 16);
#pragma unroll
    for (int d8 = 0; d8 < 2; ++d8) {
#pragma unroll
        for (int y8 = 0; y8 < 2; ++y8) {
#pragma unroll
            for (int x8 = 0; x8 < 2; ++x8) {
                int i = d8 * 4 + y8 * 2 + x8;
                wt[i] = wza[d8] * wya[y8] * wxa[x8];
                cv[i] = *(const float4*)(vb +
                    ((((size_t)(z0 + d8) * 64) + (y0 + y8)) * 64 + (x0 + x8)) * 16 + cg * 4);
            }
        }
    }
}

// ---------------------------------------------------------------------------
// K2: round-15 kernel with GEMM3 moved OFF the LDS/MFMA path: after GEMM2,
// h2 stays in f32 registers; feat = relu(h2)@W3+b3 computed with 128 fma
// against register-hoisted W3 (f32, from global — loop-invariant) and a
// 4-step __shfl_xor reduction over the 16-lane r-group. Deletes the second
// hb round-trip (32 u32 writes + 16 b128 reads + 12 MFMA + h2 conversions)
// and improves precision (h2 never rounded to bf16). b1/b2 LDS scalar reads
// hoisted out of the tile loop. Everything else verbatim round 15.
// ---------------------------------------------------------------------------
__global__ __launch_bounds__(256) void sample_mlp_mfma_kernel(
    const float* __restrict__ vols,     // [2][64][64][64][16] f32 (averaged)
    const float* __restrict__ rays,     // target_rays [2][1][64][64][8]
    const char* __restrict__ wpack_g,   // WPACK_BYTES
    const float* __restrict__ W3g,      // [128][4] f32 (global)
    const float* __restrict__ b3g,      // [4] f32 (global)
    float* __restrict__ feat)           // [2][262144][4]
{
    __shared__ __align__(16) char sm[126976];
    char* wp = sm;                       // 86016: staged wpack
    char* xs = sm + 86016;               // 8192:  x tile, 64 rows x 128B [64 hi|64 lo]
    char* hb = sm + 94208;               // 32768: h1 tile, 64 rows x 512B, col c @ 4c = hi|lo<<16

    int t = threadIdx.x;

    // ---- stage wpack ONCE ----
#pragma unroll
    for (int it = 0; it < 21; ++it) {
        int off = it * 4096 + t * 16;
        *(f32x4*)(wp + off) = *(const f32x4*)(wpack_g + off);
    }

    // ---- lane decomposition: sampling wave-local (verbatim round 13) ----
    const int w    = t >> 6;
    const int l    = t & 63;
    const int r    = l & 15;
    const int g    = l >> 4;
    const int rb   = w * 16;
    const int prow = rb + r;            // this lane's sample point row (== GEMM1 row)
    const int swzr = (r & 7) << 4;      // == (prow&7)<<4

    char*       xroww = xs + prow * 128;
    const char* xrow  = xroww;          // GEMM1 reads the same row
    const char* hrow  = hb + prow * 512;

    // ---- loop-invariant register hoists from GLOBAL (not MFMA operands) ----
    float w3r[8][4];
#pragma unroll
    for (int f = 0; f < 8; ++f)
#pragma unroll
        for (int o = 0; o < 4; ++o)
            w3r[f][o] = W3g[(16 * f + r) * 4 + o];
    float b3r[4];
#pragma unroll
    for (int o = 0; o < 4; ++o) b3r[o] = b3g[o];

    // ---- xs zero-half (k=16..31): wave-local, write ONCE ----
    {
        short4v zv4; zv4[0] = 0; zv4[1] = 0; zv4[2] = 0; zv4[3] = 0;
        *(short4v*)(xroww + ((32 + g * 8) ^ swzr)) = zv4;   // hi k=16..31
        *(short4v*)(xroww + ((96 + g * 8) ^ swzr)) = zv4;   // lo k=16..31
    }

    __syncthreads();   // wpack staged (only cross-wave dependency in the kernel)

    // ---- loop-invariant bias hoists from LDS (after barrier) ----
    const float* b1s = (const float*)(wp + OFF_B1);
    const float* b2s = (const float*)(wp + OFF_B2);
    float b1r[8], b2r[8];
#pragma unroll
    for (int f = 0; f < 8; ++f) {
        b1r[f] = b1s[16 * f + r];
        b2r[f] = b2s[16 * f + r];
    }

    // ---- prologue: gather first tile into registers ----
    float4 cv[8]; float wt[8];
    gather_pt(vols, rays, blockIdx.x, prow, g, cv, wt);

    for (int tile = blockIdx.x; tile < 8192; tile += gridDim.x) {
        const int sb = tile >> 12;
        const int n0 = (tile & 4095) << 6;
        const int nxt = tile + gridDim.x;

        // ---- combine current gather -> xs (wave-local; cvt_pk) ----
        {
            float a0 = 0.f, a1 = 0.f, a2 = 0.f, a3 = 0.f;
#pragma unroll
            for (int i = 0; i < 8; ++i) {
                a0 = fmaf(wt[i], cv[i].x, a0);
                a1 = fmaf(wt[i], cv[i].y, a1);
                a2 = fmaf(wt[i], cv[i].z, a2);
                a3 = fmaf(wt[i], cv[i].w, a3);
            }
            unsigned h01 = cvtpk(a0, a1);
            unsigned h23 = cvtpk(a2, a3);
            float l0 = a0 - asf(h01 << 16);
            float l1 = a1 - asf(h01 & 0xFFFF0000u);
            float l2 = a2 - asf(h23 << 16);
            float l3 = a3 - asf(h23 & 0xFFFF0000u);
            uint2 hv; hv.x = h01; hv.y = h23;
            uint2 lv; lv.x = cvtpk(l0, l1); lv.y = cvtpk(l2, l3);
            *(uint2*)(xroww + ((g * 8) ^ swzr))       = hv;
            *(uint2*)(xroww + ((64 + g * 8) ^ swzr))  = lv;
        }

        // ---- GEMM1: h1 = relu(x @ W1 + b1)  (3-term split, K=32 frame) ----
        short8 xh = *(const short8*)(xrow + ((g * 16) ^ swzr));
        short8 xl = *(const short8*)(xrow + ((64 + g * 16) ^ swzr));
        f32x4 acc1[8];
#pragma unroll
        for (int f = 0; f < 8; ++f) {
            float bv = b1r[f];
            f32x4 acc = {bv, bv, bv, bv};
            const char* wrow = wp + OFF_W1 + (16 * f + r) * 128;
            short8 bh = *(const short8*)(wrow + ((g * 16) ^ swzr));
            short8 bl = *(const short8*)(wrow + ((64 + g * 16) ^ swzr));
            acc = __builtin_amdgcn_mfma_f32_16x16x32_bf16(xh, bl, acc, 0, 0, 0);
            acc = __builtin_amdgcn_mfma_f32_16x16x32_bf16(xl, bh, acc, 0, 0, 0);
            acc = __builtin_amdgcn_mfma_f32_16x16x32_bf16(xh, bh, acc, 0, 0, 0);
            acc1[f] = acc;
        }
#pragma unroll
        for (int f = 0; f < 8; ++f) {
#pragma unroll
            for (int q = 0; q < 4; ++q) {
                float v = fmaxf(acc1[f][q], 0.0f);
                unsigned th = cvtpk(v, v);                 // lo16 = bf16(v)
                float lo = v - asf(th << 16);
                unsigned pk = cvtpk(v, lo);                // hi | lo<<16
                int row = rb + 4 * g + q;
                int swzh = (row & 7) << 4;
                *(unsigned*)(hb + row * 512 + ((4 * (16 * f + r)) ^ swzh)) = pk;
            }
        }

        // ---- prefetch NEXT tile's gather (drains under GEMM2/3) ----
        float4 cv2[8]; float wt2[8];
        if (nxt < 8192)
            gather_pt(vols, rays, nxt, prow, g, cv2, wt2);

        // ---- GEMM2: h2 = h1 @ W2 + b2  (K=128, 3-term split; relu deferred) ----
        f32x4 acc2[8];
#pragma unroll
        for (int f = 0; f < 8; ++f) {
            float bv = b2r[f];
            acc2[f] = (f32x4){bv, bv, bv, bv};
        }
#pragma unroll
        for (int s = 0; s < 4; ++s) {
            u32x4 v0 = *(const u32x4*)(hrow + ((s * 128 + g * 32) ^ swzr));
            u32x4 v1 = *(const u32x4*)(hrow + ((s * 128 + g * 32 + 16) ^ swzr));
            union { unsigned w4[4]; short8 s8; } uh, ul;
            uh.w4[0] = permb(v0[1], v0[0], 0x05040100u);
            ul.w4[0] = permb(v0[1], v0[0], 0x07060302u);
            uh.w4[1] = permb(v0[3], v0[2], 0x05040100u);
            ul.w4[1] = permb(v0[3], v0[2], 0x07060302u);
            uh.w4[2] = permb(v1[1], v1[0], 0x05040100u);
            ul.w4[2] = permb(v1[1], v1[0], 0x07060302u);
            uh.w4[3] = permb(v1[3], v1[2], 0x05040100u);
            ul.w4[3] = permb(v1[3], v1[2], 0x07060302u);
            short8 ah = uh.s8, al = ul.s8;
#pragma unroll
            for (int f = 0; f < 8; ++f) {
                const char* wrow = wp + OFF_W2 + (16 * f + r) * 512;
                short8 bh = *(const short8*)(wrow + ((s * 64 + g * 16) ^ swzr));
                short8 bl = *(const short8*)(wrow + ((256 + s * 64 + g * 16) ^ swzr));
                acc2[f] = __builtin_amdgcn_mfma_f32_16x16x32_bf16(ah, bl, acc2[f], 0, 0, 0);
                acc2[f] = __builtin_amdgcn_mfma_f32_16x16x32_bf16(al, bh, acc2[f], 0, 0, 0);
                acc2[f] = __builtin_amdgcn_mfma_f32_16x16x32_bf16(ah, bh, acc2[f], 0, 0, 0);
            }
        }

        // ---- GEMM3 in registers: feat = relu(h2) @ W3 + b3 (f32 exact) ----
        float part[4][4];                          // [q][o]
#pragma unroll
        for (int q = 0; q < 4; ++q)
#pragma unroll
            for (int o = 0; o < 4; ++o) part[q][o] = 0.0f;
#pragma unroll
        for (int f = 0; f < 8; ++f) {
#pragma unroll
            for (int q = 0; q < 4; ++q) {
                float hv = fmaxf(acc2[f][q], 0.0f);
#pragma unroll
                for (int o = 0; o < 4; ++o)
                    part[q][o] = fmaf(hv, w3r[f][o], part[q][o]);
            }
        }
        // reduce over the 16-lane r-group (lanes 16g..16g+15)
#pragma unroll
        for (int m = 1; m < 16; m <<= 1) {
#pragma unroll
            for (int q = 0; q < 4; ++q)
#pragma unroll
                for (int o = 0; o < 4; ++o)
                    part[q][o] += __shfl_xor(part[q][o], m, 64);
        }
        if (r < 4) {
            size_t base = ((size_t)sb << 18) + (size_t)(n0 + rb + 4 * g);
#pragma unroll
            for (int q = 0; q < 4; ++q)
                feat[(base + q) * 4 + r] = part[q][r] + b3r[r];
        }

        // ---- rotate prefetched gather into current ----
        if (nxt < 8192) {
#pragma unroll
            for (int i = 0; i < 8; ++i) { cv[i] = cv2[i]; wt[i] = wt2[i]; }
        }
    }
}

// ---------------------------------------------------------------------------
// K3: wave-parallel alpha compositing (validated round 15).
// ---------------------------------------------------------------------------
__global__ __launch_bounds__(256) void composite_wave_kernel(
    const float* __restrict__ feat,     // [2][262144][4]
    const float* __restrict__ rays,     // target_rays
    float* __restrict__ out)            // rgb [24576] then depth [8192]
{
    int t = threadIdx.x;
    int lane = t & 63;
    int gid = blockIdx.x * 4 + (t >> 6);   // pixel slot 0..8191
    int sb = gid >> 12;
    int pix = gid & 4095;
    const float* ray = rays + (size_t)pix * 8;   // sb=0 rays (reference quirk)
    float nr = ray[6], fr = ray[7];
    float dstep = (fr - nr) * (1.0f / 64.0f);

    int i = lane;                                // sample index
    float4 f = *(const float4*)(feat +
        ((size_t)sb * 262144 + (size_t)i * 4096 + pix) * 4);

    float sigma = fmaxf(f.w, 0.0f);
    float delta = (i == 63) ? 1000.0f : dstep;
    float alpha = 1.0f - expf(-sigma * delta);
    float om = 1.0f - alpha + 1e-10f;

    // inclusive product scan over lanes (Hillis-Steele)
    float prod = om;
#pragma unroll
    for (int off = 1; off < 64; off <<= 1) {
        float v = __shfl_up(prod, off, 64);
        if (lane >= off) prod *= v;
    }
    // exclusive transmittance T_i = prod_{j<i}
    float T = __shfl_up(prod, 1, 64);
    if (lane == 0) T = 1.0f;
    float wgt = alpha * T;

    float tt = ((float)i + 0.5f) * (1.0f / 64.0f);
    float zv = nr * (1.0f - tt) + fr * tt;
    float rr = wgt * (1.0f / (1.0f + expf(-f.x)));
    float gg = wgt * (1.0f / (1.0f + expf(-f.y)));
    float bb = wgt * (1.0f / (1.0f + expf(-f.z)));
    float dd = wgt * zv;

#pragma unroll
    for (int off = 32; off > 0; off >>= 1) {
        rr += __shfl_down(rr, off, 64);
        gg += __shfl_down(gg, off, 64);
        bb += __shfl_down(bb, off, 64);
        dd += __shfl_down(dd, off, 64);
    }
    if (lane == 0) {
        out[(size_t)gid * 3 + 0] = rr;
        out[(size_t)gid * 3 + 1] = gg;
        out[(size_t)gid * 3 + 2] = bb;
        out[24576 + gid] = dd;
    }
}

// ---------------------------------------------------------------------------
extern "C" void kernel_launch(void* const* d_in, const int* in_sizes, int n_in,
                              void* d_out, int out_size, void* d_ws, size_t ws_size,
                              hipStream_t stream) {
    const float* images      = (const float*)d_in[0];
    const float* target_rays = (const float*)d_in[2];
    const float* W_enc       = (const float*)d_in[3];
    const float* b_enc       = (const float*)d_in[4];
    const float* W1          = (const float*)d_in[5];
    const float* b1          = (const float*)d_in[6];
    const float* W2          = (const float*)d_in[7];
    const float* b2          = (const float*)d_in[8];
    const float* W3          = (const float*)d_in[9];
    const float* b3          = (const float*)d_in[10];

    float* ws   = (float*)d_ws;
    float* vols = ws;                                    // 2*64^3*16 f32 = 33.5 MB
    float* feat = ws + (size_t)2 * 64 * 64 * 64 * 16;    // 8 MB
    char*  wpack = (char*)(feat + (size_t)2 * 262144 * 4);
    float* out  = (float*)d_out;

    pack_weights_kernel<<<168, 256, 0, stream>>>(W1, b1, W2, b2, W3, b3, wpack);
    conv_enc_avg_kernel<<<2048, 256, 0, stream>>>(images, W_enc, b_enc, vols);
    sample_mlp_mfma_kernel<<<256, 256, 0, stream>>>(vols, target_rays, wpack,
                                                    W3, b3, feat);
    composite_wave_kernel<<<2048, 256, 0, stream>>>(feat, target_rays, out);
}

// Round 17
// 159.292 us; speedup vs baseline: 1.0720x; 1.0720x over previous
//
#include <hip/hip_runtime.h>
#include <math.h>

typedef __attribute__((ext_vector_type(8))) short short8;
typedef __attribute__((ext_vector_type(4))) short short4v;
typedef __attribute__((ext_vector_type(4))) float f32x4;
typedef __attribute__((ext_vector_type(4))) unsigned int u32x4;

// wpack v2 layout (bytes), XOR-swizzled rows (off ^= (row&7)<<4 within row):
//   w1 : 128 rows x 128B  (row n: [64B hi k=0..31][64B lo]; k>=16 zero; W1[k][n])
//   w2 : 128 rows x 512B  (row n: [256B hi k=0..127][256B lo]; W2[k][n])
//   w3 : 4 rows   x 512B  (row o: [256B hi][256B lo]; W3[k][o])
//   b1,b2 : 128 f32 each; b3 : 4 f32; zero pad to 86016
#define OFF_W1 0
#define OFF_W2 16384
#define OFF_W3 81920
#define OFF_B1 83968
#define OFF_B2 84480
#define OFF_B3 84992
#define WPACK_BYTES 86016

__device__ __forceinline__ unsigned short f2bf(float x) {
    union { float f; unsigned u; } v; v.f = x;
    unsigned r = v.u + 0x7FFF + ((v.u >> 16) & 1);   // RNE
    return (unsigned short)(r >> 16);
}
__device__ __forceinline__ float bf2f(unsigned short h) {
    union { unsigned u; float f; } v; v.u = ((unsigned)h) << 16;
    return v.f;
}
__device__ __forceinline__ float asf(unsigned u) {
    union { unsigned u; float f; } v; v.u = u; return v.f;
}
// v_cvt_pk_bf16_f32: dst.lo16 = bf16(a), dst.hi16 = bf16(b), RNE (same as f2bf)
__device__ __forceinline__ unsigned cvtpk(float a, float b) {
    unsigned d;
    asm("v_cvt_pk_bf16_f32 %0, %1, %2" : "=v"(d) : "v"(a), "v"(b));
    return d;
}
// v_perm_b32: data = {s0:bytes4-7, s1:bytes0-3}; dst.byte_i = data.byte[sel_i]
__device__ __forceinline__ unsigned permb(unsigned s0, unsigned s1, unsigned sel) {
    unsigned d;
    asm("v_perm_b32 %0, %1, %2, %3" : "=v"(d) : "v"(s0), "v"(s1), "s"(sel));
    return d;
}

// ---------------------------------------------------------------------------
// K01: fused (K1 conv | K0 pack) — the two are independent (disjoint outputs,
// read-only inputs), so one dispatch with a block-uniform branch removes a
// launch boundary. Both paths byte-identical to their validated forms.
// Blocks 0..2047: conv;  blocks 2048..2215: pack.
// ---------------------------------------------------------------------------
__global__ __launch_bounds__(256) void conv_pack_kernel(
    const float* __restrict__ images,
    const float* __restrict__ W_enc,
    const float* __restrict__ b_enc,
    float* __restrict__ vols,
    const float* __restrict__ W1, const float* __restrict__ b1,
    const float* __restrict__ W2, const float* __restrict__ b2,
    const float* __restrict__ W3, const float* __restrict__ b3,
    char* __restrict__ wp)
{
    __shared__ float wl[16 * 27];
    __shared__ float bl[16];
    int t = threadIdx.x;

    if (blockIdx.x >= 2048) {
        // ---- pack path (verbatim K0) ----
        int s = (blockIdx.x - 2048) * 256 + t;    // ushort slot
        if (s >= WPACK_BYTES / 2) return;
        int b = s * 2;
        if (b < OFF_W2) {                             // w1
            int rr = b >> 7;
            int off = (b & 127) ^ ((rr & 7) << 4);
            int k = (off & 63) >> 1;
            float x = (k < 16) ? W1[k * 128 + rr] : 0.0f;
            unsigned short hi = f2bf(x);
            *(unsigned short*)(wp + b) = (off < 64) ? hi : f2bf(x - bf2f(hi));
        } else if (b < OFF_W3) {                      // w2
            int i = b - OFF_W2;
            int rr = i >> 9;
            int off = (i & 511) ^ ((rr & 7) << 4);
            int k = (off & 255) >> 1;
            float x = W2[k * 128 + rr];
            unsigned short hi = f2bf(x);
            *(unsigned short*)(wp + b) = (off < 256) ? hi : f2bf(x - bf2f(hi));
        } else if (b < OFF_B1) {                      // w3
            int i = b - OFF_W3;
            int rr = i >> 9;                          // 0..3
            int off = (i & 511) ^ ((rr & 7) << 4);
            int k = (off & 255) >> 1;
            float x = W3[k * 4 + rr];
            unsigned short hi = f2bf(x);
            *(unsigned short*)(wp + b) = (off < 256) ? hi : f2bf(x - bf2f(hi));
        } else if (b < OFF_B3 + 16) {                 // f32 biases
            if ((b & 3) == 0) {
                float v;
                if (b < OFF_B2)      v = b1[(b - OFF_B1) >> 2];
                else if (b < OFF_B3) v = b2[(b - OFF_B2) >> 2];
                else                 v = b3[(b - OFF_B3) >> 2];
                *(float*)(wp + b) = v;
            }
        } else {
            *(unsigned short*)(wp + b) = 0;
        }
        return;
    }

    // ---- conv path (verbatim K1) ----
    int gid = blockIdx.x * 256 + t;   // 0 .. 2^19-1
    int ow = gid & 63;
    int oh = (gid >> 6) & 63;
    int dz = (gid >> 12) & 63;
    int sb = gid >> 18;               // 0..1

    for (int i = t; i < 16 * 27; i += 256) {
        int c = i / 27, r = i - c * 27;
        wl[i] = W_enc[(c * 64 + dz) * 27 + r];
    }
    if (t < 16) bl[t] = b_enc[t * 64 + dz];
    __syncthreads();

    const float* img0 = images + (size_t)((sb * 3 + 0) * 3) * (128 * 128);
    const float* img1 = images + (size_t)((sb * 3 + 1) * 3) * (128 * 128);

    float acc0[16], acc1[16];
#pragma unroll
    for (int c = 0; c < 16; ++c) { acc0[c] = 0.0f; acc1[c] = 0.0f; }

#pragma unroll
    for (int ci = 0; ci < 3; ++ci) {
#pragma unroll
        for (int kh = 0; kh < 3; ++kh) {
            int ih = oh * 2 + kh;
            if (ih >= 128) continue;
#pragma unroll
            for (int kw = 0; kw < 3; ++kw) {
                int iw = ow * 2 + kw;
                if (iw >= 128) continue;
                float p0 = img0[(ci * 128 + ih) * 128 + iw];
                float p1 = img1[(ci * 128 + ih) * 128 + iw];
                const float* w = &wl[ci * 9 + kh * 3 + kw];
#pragma unroll
                for (int c = 0; c < 16; ++c) {
                    float wv = w[c * 27];
                    acc0[c] = fmaf(p0, wv, acc0[c]);
                    acc1[c] = fmaf(p1, wv, acc1[c]);
                }
            }
        }
    }

    float* outp = vols + ((((size_t)sb * 64 + dz) * 64 + oh) * 64 + ow) * 16;
    float r[16];
#pragma unroll
    for (int c = 0; c < 16; ++c) {
        float v0 = fmaxf(acc0[c] + bl[c], 0.0f);
        float v1 = fmaxf(acc1[c] + bl[c], 0.0f);
        r[c] = (v0 + v1) * 0.5f;
    }
#pragma unroll
    for (int q = 0; q < 4; ++q) {
        float4 v = make_float4(r[q * 4], r[q * 4 + 1], r[q * 4 + 2], r[q * 4 + 3]);
        *(float4*)(outp + q * 4) = v;
    }
}

// ---------------------------------------------------------------------------
// Gather one point's 8 trilinear corners + weights into registers (no combine)
// ---------------------------------------------------------------------------
__device__ __forceinline__ void gather_pt(
    const float* __restrict__ vols, const float* __restrict__ rays,
    int tile, int prow, int cg, float4 cv[8], float wt[8])
{
    int sb = tile >> 12;
    int n0 = (tile & 4095) << 6;
    int n = n0 + prow;
    int i_s = n >> 12, pix = n & 4095;
    const float* ray = rays + ((size_t)sb * 4096 + pix) * 8;
    float ox = ray[0], oy = ray[1], oz = ray[2];
    float rdx = ray[3], rdy = ray[4], rdz = ray[5];
    float nr = ray[6], fr = ray[7];
    float tt = ((float)i_s + 0.5f) * (1.0f / 64.0f);
    float zv = nr * (1.0f - tt) + fr * tt;
    float px = fmaf(rdx, zv, ox);
    float py = fmaf(rdy, zv, oy);
    float pz = fmaf(rdz, zv, oz);
    float cx = fminf(fmaxf(px * (1.0f / 3.5f), -1.0f), 1.0f);
    float cy = fminf(fmaxf(py * (1.0f / 3.5f), -1.0f), 1.0f);
    float cz = fminf(fmaxf(pz * (1.0f / 3.5f), -1.0f), 1.0f);
    float ux = (cx + 1.0f) * 31.5f;
    float uy = (cy + 1.0f) * 31.5f;
    float uz = (cz + 1.0f) * 31.5f;
    int x0 = (int)fminf(floorf(ux), 62.0f);
    int y0 = (int)fminf(floorf(uy), 62.0f);
    int z0 = (int)fminf(floorf(uz), 62.0f);
    float fx = ux - (float)x0;
    float fy = uy - (float)y0;
    float fz = uz - (float)z0;
    float wxa[2] = {1.0f - fx, fx};
    float wya[2] = {1.0f - fy, fy};
    float wza[2] = {1.0f - fz, fz};
    const float* vb = vols + (size_t)sb * (64 * 64 * 64 * 16);
#pragma unroll
    for (int d8 = 0; d8 < 2; ++d8) {
#pragma unroll
        for (int y8 = 0; y8 < 2; ++y8) {
#pragma unroll
            for (int x8 = 0; x8 < 2; ++x8) {
                int i = d8 * 4 + y8 * 2 + x8;
                wt[i] = wza[d8] * wya[y8] * wxa[x8];
                cv[i] = *(const float4*)(vb +
                    ((((size_t)(z0 + d8) * 64) + (y0 + y8)) * 64 + (x0 + x8)) * 16 + cg * 4);
            }
        }
    }
}

// ---------------------------------------------------------------------------
// K2: round-15 kernel VERBATIM (validated, 137us). R16's in-register GEMM3
// (shfl_xor tree) REGRESSED — shfl is ds_bpermute (same LDS pipe) in a serial
// chain; reverted.
// ---------------------------------------------------------------------------
__global__ __launch_bounds__(256) void sample_mlp_mfma_kernel(
    const float* __restrict__ vols,     // [2][64][64][64][16] f32 (averaged)
    const float* __restrict__ rays,     // target_rays [2][1][64][64][8]
    const char* __restrict__ wpack_g,   // WPACK_BYTES
    float* __restrict__ feat)           // [2][262144][4]
{
    __shared__ __align__(16) char sm[126976];
    char* wp = sm;                       // 86016: staged wpack
    char* xs = sm + 86016;               // 8192:  x tile, 64 rows x 128B [64 hi|64 lo]
    char* hb = sm + 94208;               // 32768: h tile, 64 rows x 512B, col c @ 4c = hi|lo<<16

    int t = threadIdx.x;

    // ---- stage wpack ONCE ----
#pragma unroll
    for (int it = 0; it < 21; ++it) {
        int off = it * 4096 + t * 16;
        *(f32x4*)(wp + off) = *(const f32x4*)(wpack_g + off);
    }

    // ---- lane decomposition: sampling wave-local (verbatim round 13) ----
    const int w    = t >> 6;
    const int l    = t & 63;
    const int r    = l & 15;
    const int g    = l >> 4;
    const int rb   = w * 16;
    const int prow = rb + r;            // this lane's sample point row (== GEMM1 row)
    const int swzr = (r & 7) << 4;      // == (prow&7)<<4

    const float* b1s = (const float*)(wp + OFF_B1);
    const float* b2s = (const float*)(wp + OFF_B2);
    const float* b3s = (const float*)(wp + OFF_B3);
    char*       xroww = xs + prow * 128;
    const char* xrow  = xroww;          // GEMM1 reads the same row
    const char* hrow  = hb + prow * 512;
    const char* w3row = wp + OFF_W3 + (r & 3) * 512;
    const int   swz3  = (r & 3) << 4;

    // ---- xs zero-half (k=16..31): wave-local, write ONCE ----
    {
        short4v zv4; zv4[0] = 0; zv4[1] = 0; zv4[2] = 0; zv4[3] = 0;
        *(short4v*)(xroww + ((32 + g * 8) ^ swzr)) = zv4;   // hi k=16..31
        *(short4v*)(xroww + ((96 + g * 8) ^ swzr)) = zv4;   // lo k=16..31
    }

    __syncthreads();   // wpack staged (only cross-wave dependency in the kernel)

    // ---- prologue: gather first tile into registers ----
    float4 cv[8]; float wt[8];
    gather_pt(vols, rays, blockIdx.x, prow, g, cv, wt);

    for (int tile = blockIdx.x; tile < 8192; tile += gridDim.x) {
        const int sb = tile >> 12;
        const int n0 = (tile & 4095) << 6;
        const int nxt = tile + gridDim.x;

        // ---- combine current gather -> xs (wave-local; cvt_pk) ----
        {
            float a0 = 0.f, a1 = 0.f, a2 = 0.f, a3 = 0.f;
#pragma unroll
            for (int i = 0; i < 8; ++i) {
                a0 = fmaf(wt[i], cv[i].x, a0);
                a1 = fmaf(wt[i], cv[i].y, a1);
                a2 = fmaf(wt[i], cv[i].z, a2);
                a3 = fmaf(wt[i], cv[i].w, a3);
            }
            unsigned h01 = cvtpk(a0, a1);
            unsigned h23 = cvtpk(a2, a3);
            float l0 = a0 - asf(h01 << 16);
            float l1 = a1 - asf(h01 & 0xFFFF0000u);
            float l2 = a2 - asf(h23 << 16);
            float l3 = a3 - asf(h23 & 0xFFFF0000u);
            uint2 hv; hv.x = h01; hv.y = h23;
            uint2 lv; lv.x = cvtpk(l0, l1); lv.y = cvtpk(l2, l3);
            *(uint2*)(xroww + ((g * 8) ^ swzr))       = hv;
            *(uint2*)(xroww + ((64 + g * 8) ^ swzr))  = lv;
        }

        // ---- GEMM1: h1 = relu(x @ W1 + b1)  (3-term split, K=32 frame) ----
        short8 xh = *(const short8*)(xrow + ((g * 16) ^ swzr));
        short8 xl = *(const short8*)(xrow + ((64 + g * 16) ^ swzr));
        f32x4 acc1[8];
#pragma unroll
        for (int f = 0; f < 8; ++f) {
            float bv = b1s[16 * f + r];
            f32x4 acc = {bv, bv, bv, bv};
            const char* wrow = wp + OFF_W1 + (16 * f + r) * 128;
            short8 bh = *(const short8*)(wrow + ((g * 16) ^ swzr));
            short8 bl = *(const short8*)(wrow + ((64 + g * 16) ^ swzr));
            acc = __builtin_amdgcn_mfma_f32_16x16x32_bf16(xh, bl, acc, 0, 0, 0);
            acc = __builtin_amdgcn_mfma_f32_16x16x32_bf16(xl, bh, acc, 0, 0, 0);
            acc = __builtin_amdgcn_mfma_f32_16x16x32_bf16(xh, bh, acc, 0, 0, 0);
            acc1[f] = acc;
        }
#pragma unroll
        for (int f = 0; f < 8; ++f) {
#pragma unroll
            for (int q = 0; q < 4; ++q) {
                float v = fmaxf(acc1[f][q], 0.0f);
                unsigned th = cvtpk(v, v);                 // lo16 = bf16(v)
                float lo = v - asf(th << 16);
                unsigned pk = cvtpk(v, lo);                // hi | lo<<16
                int row = rb + 4 * g + q;
                int swzh = (row & 7) << 4;
                *(unsigned*)(hb + row * 512 + ((4 * (16 * f + r)) ^ swzh)) = pk;
            }
        }

        // ---- prefetch NEXT tile's gather (drains under GEMM2/3) ----
        float4 cv2[8]; float wt2[8];
        if (nxt < 8192)
            gather_pt(vols, rays, nxt, prow, g, cv2, wt2);

        // ---- GEMM2: h2 = relu(h1 @ W2 + b2)  (K=128, 3-term split) ----
        f32x4 acc2[8];
#pragma unroll
        for (int f = 0; f < 8; ++f) {
            float bv = b2s[16 * f + r];
            acc2[f] = (f32x4){bv, bv, bv, bv};
        }
#pragma unroll
        for (int s = 0; s < 4; ++s) {
            u32x4 v0 = *(const u32x4*)(hrow + ((s * 128 + g * 32) ^ swzr));
            u32x4 v1 = *(const u32x4*)(hrow + ((s * 128 + g * 32 + 16) ^ swzr));
            union { unsigned w4[4]; short8 s8; } uh, ul;
            uh.w4[0] = permb(v0[1], v0[0], 0x05040100u);
            ul.w4[0] = permb(v0[1], v0[0], 0x07060302u);
            uh.w4[1] = permb(v0[3], v0[2], 0x05040100u);
            ul.w4[1] = permb(v0[3], v0[2], 0x07060302u);
            uh.w4[2] = permb(v1[1], v1[0], 0x05040100u);
            ul.w4[2] = permb(v1[1], v1[0], 0x07060302u);
            uh.w4[3] = permb(v1[3], v1[2], 0x05040100u);
            ul.w4[3] = permb(v1[3], v1[2], 0x07060302u);
            short8 ah = uh.s8, al = ul.s8;
#pragma unroll
            for (int f = 0; f < 8; ++f) {
                const char* wrow = wp + OFF_W2 + (16 * f + r) * 512;
                short8 bh = *(const short8*)(wrow + ((s * 64 + g * 16) ^ swzr));
                short8 bl = *(const short8*)(wrow + ((256 + s * 64 + g * 16) ^ swzr));
                acc2[f] = __builtin_amdgcn_mfma_f32_16x16x32_bf16(ah, bl, acc2[f], 0, 0, 0);
                acc2[f] = __builtin_amdgcn_mfma_f32_16x16x32_bf16(al, bh, acc2[f], 0, 0, 0);
                acc2[f] = __builtin_amdgcn_mfma_f32_16x16x32_bf16(ah, bh, acc2[f], 0, 0, 0);
            }
        }
#pragma unroll
        for (int f = 0; f < 8; ++f) {
#pragma unroll
            for (int q = 0; q < 4; ++q) {
                float v = fmaxf(acc2[f][q], 0.0f);
                unsigned th = cvtpk(v, v);
                float lo = v - asf(th << 16);
                unsigned pk = cvtpk(v, lo);
                int row = rb + 4 * g + q;
                int swzh = (row & 7) << 4;
                *(unsigned*)(hb + row * 512 + ((4 * (16 * f + r)) ^ swzh)) = pk;
            }
        }

        // ---- GEMM3: feat = h2 @ W3 + b3  (3-term split) ----
        float bv3 = b3s[r & 3];
        f32x4 acc3 = (f32x4){bv3, bv3, bv3, bv3};
#pragma unroll
        for (int s = 0; s < 4; ++s) {
            u32x4 v0 = *(const u32x4*)(hrow + ((s * 128 + g * 32) ^ swzr));
            u32x4 v1 = *(const u32x4*)(hrow + ((s * 128 + g * 32 + 16) ^ swzr));
            union { unsigned w4[4]; short8 s8; } uh, ul;
            uh.w4[0] = permb(v0[1], v0[0], 0x05040100u);
            ul.w4[0] = permb(v0[1], v0[0], 0x07060302u);
            uh.w4[1] = permb(v0[3], v0[2], 0x05040100u);
            ul.w4[1] = permb(v0[3], v0[2], 0x07060302u);
            uh.w4[2] = permb(v1[1], v1[0], 0x05040100u);
            ul.w4[2] = permb(v1[1], v1[0], 0x07060302u);
            uh.w4[3] = permb(v1[3], v1[2], 0x05040100u);
            ul.w4[3] = permb(v1[3], v1[2], 0x07060302u);
            short8 ah = uh.s8, al = ul.s8;
            short8 bh = *(const short8*)(w3row + ((s * 64 + g * 16) ^ swz3));
            short8 bl = *(const short8*)(w3row + ((256 + s * 64 + g * 16) ^ swz3));
            acc3 = __builtin_amdgcn_mfma_f32_16x16x32_bf16(ah, bl, acc3, 0, 0, 0);
            acc3 = __builtin_amdgcn_mfma_f32_16x16x32_bf16(al, bh, acc3, 0, 0, 0);
            acc3 = __builtin_amdgcn_mfma_f32_16x16x32_bf16(ah, bh, acc3, 0, 0, 0);
        }
        if (r < 4) {
            size_t base = ((size_t)sb << 18) + (size_t)(n0 + rb + 4 * g);
#pragma unroll
            for (int q = 0; q < 4; ++q)
                feat[(base + q) * 4 + r] = acc3[q];
        }

        // ---- rotate prefetched gather into current ----
        if (nxt < 8192) {
#pragma unroll
            for (int i = 0; i < 8; ++i) { cv[i] = cv2[i]; wt[i] = wt2[i]; }
        }
    }
}

// ---------------------------------------------------------------------------
// K3: wave-parallel alpha compositing (validated round 15).
// ---------------------------------------------------------------------------
__global__ __launch_bounds__(256) void composite_wave_kernel(
    const float* __restrict__ feat,     // [2][262144][4]
    const float* __restrict__ rays,     // target_rays
    float* __restrict__ out)            // rgb [24576] then depth [8192]
{
    int t = threadIdx.x;
    int lane = t & 63;
    int gid = blockIdx.x * 4 + (t >> 6);   // pixel slot 0..8191
    int sb = gid >> 12;
    int pix = gid & 4095;
    const float* ray = rays + (size_t)pix * 8;   // sb=0 rays (reference quirk)
    float nr = ray[6], fr = ray[7];
    float dstep = (fr - nr) * (1.0f / 64.0f);

    int i = lane;                                // sample index
    float4 f = *(const float4*)(feat +
        ((size_t)sb * 262144 + (size_t)i * 4096 + pix) * 4);

    float sigma = fmaxf(f.w, 0.0f);
    float delta = (i == 63) ? 1000.0f : dstep;
    float alpha = 1.0f - expf(-sigma * delta);
    float om = 1.0f - alpha + 1e-10f;

    // inclusive product scan over lanes (Hillis-Steele)
    float prod = om;
#pragma unroll
    for (int off = 1; off < 64; off <<= 1) {
        float v = __shfl_up(prod, off, 64);
        if (lane >= off) prod *= v;
    }
    // exclusive transmittance T_i = prod_{j<i}
    float T = __shfl_up(prod, 1, 64);
    if (lane == 0) T = 1.0f;
    float wgt = alpha * T;

    float tt = ((float)i + 0.5f) * (1.0f / 64.0f);
    float zv = nr * (1.0f - tt) + fr * tt;
    float rr = wgt * (1.0f / (1.0f + expf(-f.x)));
    float gg = wgt * (1.0f / (1.0f + expf(-f.y)));
    float bb = wgt * (1.0f / (1.0f + expf(-f.z)));
    float dd = wgt * zv;

#pragma unroll
    for (int off = 32; off > 0; off >>= 1) {
        rr += __shfl_down(rr, off, 64);
        gg += __shfl_down(gg, off, 64);
        bb += __shfl_down(bb, off, 64);
        dd += __shfl_down(dd, off, 64);
    }
    if (lane == 0) {
        out[(size_t)gid * 3 + 0] = rr;
        out[(size_t)gid * 3 + 1] = gg;
        out[(size_t)gid * 3 + 2] = bb;
        out[24576 + gid] = dd;
    }
}

// ---------------------------------------------------------------------------
extern "C" void kernel_launch(void* const* d_in, const int* in_sizes, int n_in,
                              void* d_out, int out_size, void* d_ws, size_t ws_size,
                              hipStream_t stream) {
    const float* images      = (const float*)d_in[0];
    const float* target_rays = (const float*)d_in[2];
    const float* W_enc       = (const float*)d_in[3];
    const float* b_enc       = (const float*)d_in[4];
    const float* W1          = (const float*)d_in[5];
    const float* b1          = (const float*)d_in[6];
    const float* W2          = (const float*)d_in[7];
    const float* b2          = (const float*)d_in[8];
    const float* W3          = (const float*)d_in[9];
    const float* b3          = (const float*)d_in[10];

    float* ws   = (float*)d_ws;
    float* vols = ws;                                    // 2*64^3*16 f32 = 33.5 MB
    float* feat = ws + (size_t)2 * 64 * 64 * 64 * 16;    // 8 MB
    char*  wpack = (char*)(feat + (size_t)2 * 262144 * 4);
    float* out  = (float*)d_out;

    conv_pack_kernel<<<2216, 256, 0, stream>>>(images, W_enc, b_enc, vols,
                                               W1, b1, W2, b2, W3, b3, wpack);
    sample_mlp_mfma_kernel<<<256, 256, 0, stream>>>(vols, target_rays, wpack, feat);
    composite_wave_kernel<<<2048, 256, 0, stream>>>(feat, target_rays, out);
}